// Round 2
// baseline (17635.390 us; speedup 1.0000x reference)
//
#include <hip/hip_runtime.h>
#include <cstdint>
#include <cstddef>

typedef __bf16 bf16;
typedef float f32x4 __attribute__((ext_vector_type(4)));
typedef bf16 bf16x8 __attribute__((ext_vector_type(8)));
typedef bf16 bf16x4 __attribute__((ext_vector_type(4)));

#define AS1 __attribute__((address_space(1)))
#define AS3 __attribute__((address_space(3)))

__device__ __forceinline__ void gload_lds16(const void* g, void* l) {
  __builtin_amdgcn_global_load_lds((AS1 void*)g, (AS3 void*)l, 16, 0, 0);
}

// ---------------- init: combined biases + barrier flags ----------------
__global__ __launch_bounds__(256) void init_misc(
    const float* __restrict__ bih0, const float* __restrict__ bhh0,
    const float* __restrict__ bih1, const float* __restrict__ bhh1,
    float* __restrict__ bsum0, float* __restrict__ bsum1, unsigned* __restrict__ flags) {
  int i = blockIdx.x * 256 + threadIdx.x;
  if (i < 4096) {
    bsum0[i] = bih0[i] + bhh0[i];
    bsum1[i] = bih1[i] + bhh1[i];
  }
  if (i < 192 * 32) flags[i] = 0u;
}

// ---------------- embedding gather -> bf16, row = t*16 + b ----------------
__global__ __launch_bounds__(256) void embed_gather(
    const int* __restrict__ x, const float* __restrict__ emb, bf16* __restrict__ xe, int T) {
  int row = blockIdx.x;           // t*16 + b
  int t = row >> 4, b = row & 15;
  int tok = x[b * T + t];
  int cix = threadIdx.x << 2;
  f32x4 v = *(const f32x4*)(emb + ((size_t)tok << 10) + cix);
  bf16x4 o;
  for (int j = 0; j < 4; ++j) o[j] = (bf16)v[j];
  *(bf16x4*)(xe + ((size_t)row << 10) + cix) = o;
}

// ---------------- GEMM: C[M,N] = A[M,K](bf16) * W[N,K](f32->bf16)^T + bias ----------------
template <int OUTMODE>
__global__ __launch_bounds__(256) void gemm_bf16(
    const bf16* __restrict__ A, const float* __restrict__ Bw,
    const float* __restrict__ bias, float* __restrict__ C,
    int M, int N, int K, int Tdim) {
  __shared__ bf16 aL[2][128 * 32];
  __shared__ bf16 bL[2][128 * 32];
  const int tid = threadIdx.x;
  const int l = tid & 63, w = tid >> 6;
  const int nbm = M >> 7;
  const int bm = blockIdx.x % nbm;
  const int bn = blockIdx.x / nbm;
  const int wr = (w >> 1) << 6, wc = (w & 1) << 6;
  const int NT = K >> 5;
  const int r16 = l & 15, kq = l >> 4;

  f32x4 acc[4][4];
  for (int m = 0; m < 4; ++m)
    for (int n = 0; n < 4; ++n) acc[m][n] = (f32x4){0.f, 0.f, 0.f, 0.f};

  for (int i = 0; i < 2; ++i) {
    int lin = tid + (i << 8);
    int r = lin >> 2, s = lin & 3, c = s ^ (r & 3);
    gload_lds16(A + (size_t)((bm << 7) + r) * K + (c << 3), &aL[0][lin << 3]);
  }
  for (int i = 0; i < 2; ++i) {
    int lin = tid + (i << 8);
    int r = lin >> 2, c = lin & 3;
    const float* src = Bw + (size_t)((bn << 7) + r) * K + (c << 3);
    f32x4 v0 = *(const f32x4*)src;
    f32x4 v1 = *(const f32x4*)(src + 4);
    bf16x8 o;
    for (int j = 0; j < 4; ++j) { o[j] = (bf16)v0[j]; o[j + 4] = (bf16)v1[j]; }
    *(bf16x8*)&bL[0][(r << 5) + ((c ^ (r & 3)) << 3)] = o;
  }
  __syncthreads();

  for (int kt = 0; kt < NT; ++kt) {
    const int cur = kt & 1;
    const bool pf = (kt + 1 < NT);
    f32x4 bv0[2], bv1[2];
    int br_[2], bs_[2];
    if (pf) {
      for (int i = 0; i < 2; ++i) {
        int lin = tid + (i << 8);
        int r = lin >> 2, s = lin & 3, c = s ^ (r & 3);
        gload_lds16(A + (size_t)((bm << 7) + r) * K + ((kt + 1) << 5) + (c << 3),
                    &aL[cur ^ 1][lin << 3]);
      }
      for (int i = 0; i < 2; ++i) {
        int lin = tid + (i << 8);
        int r = lin >> 2, c = lin & 3;
        const float* src = Bw + (size_t)((bn << 7) + r) * K + ((kt + 1) << 5) + (c << 3);
        bv0[i] = *(const f32x4*)src;
        bv1[i] = *(const f32x4*)(src + 4);
        br_[i] = r;
        bs_[i] = c ^ (r & 3);
      }
    }
    bf16x8 af[4], bfr[4];
    for (int m = 0; m < 4; ++m) {
      int row = wr + (m << 4) + r16;
      int ch = kq ^ (row & 3);
      af[m] = *(const bf16x8*)&aL[cur][(row << 5) + (ch << 3)];
    }
    for (int n = 0; n < 4; ++n) {
      int row = wc + (n << 4) + r16;
      int ch = kq ^ (row & 3);
      bfr[n] = *(const bf16x8*)&bL[cur][(row << 5) + (ch << 3)];
    }
    for (int m = 0; m < 4; ++m)
      for (int n = 0; n < 4; ++n)
        acc[m][n] = __builtin_amdgcn_mfma_f32_16x16x32_bf16(af[m], bfr[n], acc[m][n], 0, 0, 0);
    if (pf) {
      for (int i = 0; i < 2; ++i) {
        bf16x8 o;
        for (int j = 0; j < 4; ++j) { o[j] = (bf16)bv0[i][j]; o[j + 4] = (bf16)bv1[i][j]; }
        *(bf16x8*)&bL[cur ^ 1][(br_[i] << 5) + (bs_[i] << 3)] = o;
      }
    }
    __syncthreads();
  }

  float bvv[4];
  for (int n = 0; n < 4; ++n) bvv[n] = bias[(bn << 7) + wc + (n << 4) + r16];
  for (int m = 0; m < 4; ++m) {
    int Rbase = (bm << 7) + wr + (m << 4) + (kq << 2);
    for (int r = 0; r < 4; ++r) {
      int R = Rbase + r;
      size_t rowoff;
      if (OUTMODE == 0) {
        rowoff = (size_t)R * N;
      } else {
        int tt = R >> 4, bb = R & 15;
        rowoff = ((size_t)bb * Tdim + tt) * N;
      }
      for (int n = 0; n < 4; ++n)
        C[rowoff + (bn << 7) + wc + (n << 4) + r16] = acc[m][n][r] + bvv[n];
    }
  }
}

// ---------------- fused 2-layer persistent LSTM (wavefront pipelined) ----------------
// Blocks 0..63: layer 0, 16 h-cols each, Whh0 slice (64 rows x 1024) in LDS.
// Blocks 64..191: layer 1, 8 h-cols each, Wih1 + Whh1 slices (32+32 rows) in LDS.
// Global step s: L0 computes h0[s]; L1 computes h1[s-1]. 512 grid barriers via
// per-block padded flags (contention-free release-stores + parallel polling).
__global__ __launch_bounds__(256, 1) void lstm_fused(
    const float* __restrict__ gx,    // [T*16][4096] = xe@Wih0^T + bsum0
    const float* __restrict__ Whh0,  // [4096][1024] f32
    const float* __restrict__ Wih1,  // [4096][1024] f32
    const float* __restrict__ Whh1,  // [4096][1024] f32
    const float* __restrict__ bsum1, // [4096]
    bf16* __restrict__ hs0,          // [T*16][1024]
    bf16* __restrict__ hs1,          // [T*16][1024]
    unsigned* __restrict__ flags,    // [192*32], zeroed
    int T) {
  __shared__ bf16 wlds[64 * 1024];     // 128 KiB, swizzled (chunk ^= row&7)
  __shared__ float glds[4 * 16 * 16];  // gate exchange
  const int tid = threadIdx.x;
  const int l = tid & 63, w = tid >> 6;
  const int bid = blockIdx.x;
  const bool L0 = bid < 64;
  const int r16 = l & 15, kq = l >> 4, rx = r16 & 7;
  const int G1 = 192;

  // ---- stage weight slices to LDS (f32 -> bf16, swizzled) ----
  if (L0) {
    const int j0s = bid << 4;
    for (int it = 0; it < 32; ++it) {
      int lin = tid + (it << 8);
      int row = lin >> 7, cs = lin & 127, c = cs ^ (row & 7);
      int g = row >> 4, n = row & 15;
      const float* src = Whh0 + (size_t)(g * 1024 + j0s + n) * 1024 + (c << 3);
      f32x4 v0 = *(const f32x4*)src;
      f32x4 v1 = *(const f32x4*)(src + 4);
      bf16x8 o;
      for (int j = 0; j < 4; ++j) { o[j] = (bf16)v0[j]; o[j + 4] = (bf16)v1[j]; }
      *(bf16x8*)(wlds + (row << 10) + (cs << 3)) = o;
    }
  } else {
    const int j0s = (bid - 64) << 3;
    for (int it = 0; it < 32; ++it) {
      int lin = tid + (it << 8);
      int row = lin >> 7, cs = lin & 127, c = cs ^ (row & 7);
      int m = row >> 5, rr = row & 31, g = rr >> 3, n = rr & 7;
      const float* W = m ? Whh1 : Wih1;
      const float* src = W + (size_t)(g * 1024 + j0s + n) * 1024 + (c << 3);
      f32x4 v0 = *(const f32x4*)src;
      f32x4 v1 = *(const f32x4*)(src + 4);
      bf16x8 o;
      for (int j = 0; j < 4; ++j) { o[j] = (bf16)v0[j]; o[j + 4] = (bf16)v1[j]; }
      *(bf16x8*)(wlds + (row << 10) + (cs << 3)) = o;
    }
  }
  __syncthreads();

  const int bidx = tid >> 4, jl = tid & 15;  // layer-0 fusion mapping
  const int b1 = tid >> 3, j1 = tid & 7;     // layer-1 fusion mapping (tid<128)
  float cst = 0.f;
  float bi_ = 0.f, bf_ = 0.f, bg_ = 0.f, bo_ = 0.f;
  int j0;
  if (L0) {
    j0 = bid << 4;
  } else {
    j0 = (bid - 64) << 3;
    if (tid < 128) {
      bi_ = bsum1[j0 + j1];
      bf_ = bsum1[1024 + j0 + j1];
      bg_ = bsum1[2048 + j0 + j1];
      bo_ = bsum1[3072 + j0 + j1];
    }
  }
  unsigned* myflag = flags + (size_t)bid * 32;

  for (int s = 0; s <= T; ++s) {
    if (L0) {
      if (s < T) {
        const int t = s;
        const float* gp = gx + ((((size_t)t << 4) + bidx) << 12) + j0 + jl;
        float gi = gp[0], gf = gp[1024], gg2 = gp[2048], go = gp[3072];
        f32x4 acc = (f32x4){0.f, 0.f, 0.f, 0.f};
        f32x4 acc2 = (f32x4){0.f, 0.f, 0.f, 0.f};
        if (t > 0) {
          const bf16* hp = hs0 + ((size_t)(t - 1) << 14) + (r16 << 10) + (kq << 3);
          const bf16* wb = wlds + (((w << 4) + r16) << 10);
#pragma unroll 8
          for (int kk = 0; kk < 32; kk += 2) {
            bf16x8 a0 = *(const bf16x8*)(hp + (kk << 5));
            bf16x8 a1 = *(const bf16x8*)(hp + ((kk + 1) << 5));
            acc = __builtin_amdgcn_mfma_f32_16x16x32_bf16(
                a0, *(const bf16x8*)(wb + ((((kk << 2) + kq) ^ rx) << 3)), acc, 0, 0, 0);
            acc2 = __builtin_amdgcn_mfma_f32_16x16x32_bf16(
                a1, *(const bf16x8*)(wb + (((((kk + 1) << 2) + kq) ^ rx) << 3)), acc2, 0, 0, 0);
          }
        }
        for (int r = 0; r < 4; ++r)
          glds[(w << 8) + (((kq << 2) + r) << 4) + r16] = acc[r] + acc2[r];
        __syncthreads();
        float xi = glds[(bidx << 4) + jl] + gi;
        float xf = glds[256 + (bidx << 4) + jl] + gf;
        float xg = glds[512 + (bidx << 4) + jl] + gg2;
        float xo = glds[768 + (bidx << 4) + jl] + go;
        float ig = 1.f / (1.f + __expf(-xi));
        float fg = 1.f / (1.f + __expf(-xf));
        float eg = __expf(2.f * xg);
        float gg = 1.f - 2.f / (eg + 1.f);
        float og = 1.f / (1.f + __expf(-xo));
        cst = fg * cst + ig * gg;
        float ec = __expf(2.f * cst);
        float th = 1.f - 2.f / (ec + 1.f);
        hs0[((((size_t)t << 4) + bidx) << 10) + j0 + jl] = (bf16)(og * th);
      }
    } else {
      if (s >= 1) {
        const int t1 = s - 1;
        f32x4 acc0 = (f32x4){0.f, 0.f, 0.f, 0.f};
        f32x4 acc1 = (f32x4){0.f, 0.f, 0.f, 0.f};
        const bf16* hp0 = hs0 + ((size_t)t1 << 14) + (r16 << 10) + (kq << 3);
        const bf16* wb0 = wlds + (((w << 3) + rx) << 10);         // Wih1 rows
        const bf16* wb1 = wlds + ((32 + (w << 3) + rx) << 10);    // Whh1 rows
#pragma unroll 8
        for (int kk = 0; kk < 32; ++kk) {
          bf16x8 a0 = *(const bf16x8*)(hp0 + (kk << 5));
          acc0 = __builtin_amdgcn_mfma_f32_16x16x32_bf16(
              a0, *(const bf16x8*)(wb0 + ((((kk << 2) + kq) ^ rx) << 3)), acc0, 0, 0, 0);
        }
        if (t1 > 0) {
          const bf16* hp1 = hs1 + ((size_t)(t1 - 1) << 14) + (r16 << 10) + (kq << 3);
#pragma unroll 8
          for (int kk = 0; kk < 32; ++kk) {
            bf16x8 a1 = *(const bf16x8*)(hp1 + (kk << 5));
            acc1 = __builtin_amdgcn_mfma_f32_16x16x32_bf16(
                a1, *(const bf16x8*)(wb1 + ((((kk << 2) + kq) ^ rx) << 3)), acc1, 0, 0, 0);
          }
        }
        for (int r = 0; r < 4; ++r)
          glds[(w << 8) + (((kq << 2) + r) << 4) + r16] = acc0[r] + acc1[r];
        __syncthreads();
        if (tid < 128) {
          float xi = glds[(b1 << 4) + j1] + bi_;
          float xf = glds[256 + (b1 << 4) + j1] + bf_;
          float xg = glds[512 + (b1 << 4) + j1] + bg_;
          float xo = glds[768 + (b1 << 4) + j1] + bo_;
          float ig = 1.f / (1.f + __expf(-xi));
          float fg = 1.f / (1.f + __expf(-xf));
          float eg = __expf(2.f * xg);
          float gg = 1.f - 2.f / (eg + 1.f);
          float og = 1.f / (1.f + __expf(-xo));
          cst = fg * cst + ig * gg;
          float ec = __expf(2.f * cst);
          float th = 1.f - 2.f / (ec + 1.f);
          hs1[((((size_t)t1 << 4) + b1) << 10) + j0 + j1] = (bf16)(og * th);
        }
      }
    }
    // ---- grid barrier (contention-free flag array) ----
    if (s < T) {
      __threadfence();
      __syncthreads();
      if (tid == 0)
        __hip_atomic_store(myflag, (unsigned)(s + 1), __ATOMIC_RELEASE, __HIP_MEMORY_SCOPE_AGENT);
      if (w < 3) {
        unsigned* fp = flags + (size_t)((w << 6) + l) * 32;
        while (__hip_atomic_load(fp, __ATOMIC_RELAXED, __HIP_MEMORY_SCOPE_AGENT) < (unsigned)(s + 1))
          __builtin_amdgcn_s_sleep(1);
      }
      __syncthreads();
      __threadfence();
    }
    (void)G1;
  }
}

extern "C" void kernel_launch(void* const* d_in, const int* in_sizes, int n_in,
                              void* d_out, int out_size, void* d_ws, size_t ws_size,
                              hipStream_t stream) {
  const int* x = (const int*)d_in[0];
  const float* emb = (const float*)d_in[1];
  const float* Wih0 = (const float*)d_in[2];
  const float* Whh0 = (const float*)d_in[3];
  const float* bih0 = (const float*)d_in[4];
  const float* bhh0 = (const float*)d_in[5];
  const float* Wih1 = (const float*)d_in[6];
  const float* Whh1 = (const float*)d_in[7];
  const float* bih1 = (const float*)d_in[8];
  const float* bhh1 = (const float*)d_in[9];
  const float* Wout = (const float*)d_in[10];
  const float* bout = (const float*)d_in[11];

  const int T = 512, H = 1024, V = 32000;
  const int M = T * 16;
  const size_t bfb = (size_t)M * H * 2;  // 16 MiB bf16 plane

  char* p = (char*)d_ws;
  bf16* hs1 = (bf16*)p;           p += bfb;      // must survive into projection -> ws
  float* bsum0 = (float*)p;       p += 4096 * 4;
  float* bsum1 = (float*)p;       p += 4096 * 4;
  unsigned* flags = (unsigned*)p; p += 192 * 32 * 4;
  size_t base_need = (size_t)(p - (char*)d_ws);
  bf16 *xe, *hs0;
  if (ws_size >= base_need + 2 * bfb) {
    xe = (bf16*)p;
    hs0 = (bf16*)(p + bfb);
  } else {  // d_out tail is dead until projection overwrites it
    char* tail = (char*)d_out + (size_t)out_size * 4 - 2 * bfb;
    xe = (bf16*)tail;
    hs0 = (bf16*)(tail + bfb);
  }
  float* gx = (float*)d_out;  // 134 MB scratch at head of d_out

  init_misc<<<24, 256, 0, stream>>>(bih0, bhh0, bih1, bhh1, bsum0, bsum1, flags);
  embed_gather<<<M, 256, 0, stream>>>(x, emb, xe, T);
  gemm_bf16<0><<<(M / 128) * (4096 / 128), 256, 0, stream>>>(xe, Wih0, bsum0, gx, M, 4096, H, 0);
  lstm_fused<<<192, 256, 0, stream>>>(gx, Whh0, Wih1, Whh1, bsum1, hs0, hs1, flags, T);
  gemm_bf16<1><<<(M / 128) * (V / 128), 256, 0, stream>>>(hs1, Wout, bout, (float*)d_out, M, V, H, T);
}

// Round 3
// 7360.967 us; speedup vs baseline: 2.3958x; 2.3958x over previous
//
#include <hip/hip_runtime.h>
#include <cstdint>
#include <cstddef>

typedef __bf16 bf16;
typedef float f32x4 __attribute__((ext_vector_type(4)));
typedef bf16 bf16x8 __attribute__((ext_vector_type(8)));
typedef bf16 bf16x4 __attribute__((ext_vector_type(4)));

#define AS1 __attribute__((address_space(1)))
#define AS3 __attribute__((address_space(3)))

__device__ __forceinline__ void gload_lds16(const void* g, void* l) {
  __builtin_amdgcn_global_load_lds((AS1 void*)g, (AS3 void*)l, 16, 0, 0);
}

#define NBLK 192
#define FSTR 32  // flag stride in unsigned (128B)

// ---------------- init: combined biases + barrier flags ----------------
__global__ __launch_bounds__(256) void init_misc(
    const float* __restrict__ bih0, const float* __restrict__ bhh0,
    const float* __restrict__ bih1, const float* __restrict__ bhh1,
    float* __restrict__ bsum0, float* __restrict__ bsum1, unsigned* __restrict__ flags) {
  int i = blockIdx.x * 256 + threadIdx.x;
  if (i < 4096) {
    bsum0[i] = bih0[i] + bhh0[i];
    bsum1[i] = bih1[i] + bhh1[i];
  }
  if (i < NBLK * FSTR + 64) flags[i] = 0u;
}

// ---------------- embedding gather -> bf16, row = t*16 + b ----------------
__global__ __launch_bounds__(256) void embed_gather(
    const int* __restrict__ x, const float* __restrict__ emb, bf16* __restrict__ xe, int T) {
  int row = blockIdx.x;           // t*16 + b
  int t = row >> 4, b = row & 15;
  int tok = x[b * T + t];
  int cix = threadIdx.x << 2;
  f32x4 v = *(const f32x4*)(emb + ((size_t)tok << 10) + cix);
  bf16x4 o;
  for (int j = 0; j < 4; ++j) o[j] = (bf16)v[j];
  *(bf16x4*)(xe + ((size_t)row << 10) + cix) = o;
}

// ---------------- GEMM: C[M,N] = A[M,K](bf16) * W[N,K](f32->bf16)^T + bias ----------------
template <int OUTMODE>
__global__ __launch_bounds__(256) void gemm_bf16(
    const bf16* __restrict__ A, const float* __restrict__ Bw,
    const float* __restrict__ bias, float* __restrict__ C,
    int M, int N, int K, int Tdim) {
  __shared__ bf16 aL[2][128 * 32];
  __shared__ bf16 bL[2][128 * 32];
  const int tid = threadIdx.x;
  const int l = tid & 63, w = tid >> 6;
  const int nbm = M >> 7;
  const int bm = blockIdx.x % nbm;
  const int bn = blockIdx.x / nbm;
  const int wr = (w >> 1) << 6, wc = (w & 1) << 6;
  const int NT = K >> 5;
  const int r16 = l & 15, kq = l >> 4;

  f32x4 acc[4][4];
  for (int m = 0; m < 4; ++m)
    for (int n = 0; n < 4; ++n) acc[m][n] = (f32x4){0.f, 0.f, 0.f, 0.f};

  for (int i = 0; i < 2; ++i) {
    int lin = tid + (i << 8);
    int r = lin >> 2, s = lin & 3, c = s ^ (r & 3);
    gload_lds16(A + (size_t)((bm << 7) + r) * K + (c << 3), &aL[0][lin << 3]);
  }
  for (int i = 0; i < 2; ++i) {
    int lin = tid + (i << 8);
    int r = lin >> 2, c = lin & 3;
    const float* src = Bw + (size_t)((bn << 7) + r) * K + (c << 3);
    f32x4 v0 = *(const f32x4*)src;
    f32x4 v1 = *(const f32x4*)(src + 4);
    bf16x8 o;
    for (int j = 0; j < 4; ++j) { o[j] = (bf16)v0[j]; o[j + 4] = (bf16)v1[j]; }
    *(bf16x8*)&bL[0][(r << 5) + ((c ^ (r & 3)) << 3)] = o;
  }
  __syncthreads();

  for (int kt = 0; kt < NT; ++kt) {
    const int cur = kt & 1;
    const bool pf = (kt + 1 < NT);
    f32x4 bv0[2], bv1[2];
    int br_[2], bs_[2];
    if (pf) {
      for (int i = 0; i < 2; ++i) {
        int lin = tid + (i << 8);
        int r = lin >> 2, s = lin & 3, c = s ^ (r & 3);
        gload_lds16(A + (size_t)((bm << 7) + r) * K + ((kt + 1) << 5) + (c << 3),
                    &aL[cur ^ 1][lin << 3]);
      }
      for (int i = 0; i < 2; ++i) {
        int lin = tid + (i << 8);
        int r = lin >> 2, c = lin & 3;
        const float* src = Bw + (size_t)((bn << 7) + r) * K + ((kt + 1) << 5) + (c << 3);
        bv0[i] = *(const f32x4*)src;
        bv1[i] = *(const f32x4*)(src + 4);
        br_[i] = r;
        bs_[i] = c ^ (r & 3);
      }
    }
    bf16x8 af[4], bfr[4];
    for (int m = 0; m < 4; ++m) {
      int row = wr + (m << 4) + r16;
      int ch = kq ^ (row & 3);
      af[m] = *(const bf16x8*)&aL[cur][(row << 5) + (ch << 3)];
    }
    for (int n = 0; n < 4; ++n) {
      int row = wc + (n << 4) + r16;
      int ch = kq ^ (row & 3);
      bfr[n] = *(const bf16x8*)&bL[cur][(row << 5) + (ch << 3)];
    }
    for (int m = 0; m < 4; ++m)
      for (int n = 0; n < 4; ++n)
        acc[m][n] = __builtin_amdgcn_mfma_f32_16x16x32_bf16(af[m], bfr[n], acc[m][n], 0, 0, 0);
    if (pf) {
      for (int i = 0; i < 2; ++i) {
        bf16x8 o;
        for (int j = 0; j < 4; ++j) { o[j] = (bf16)bv0[i][j]; o[j + 4] = (bf16)bv1[i][j]; }
        *(bf16x8*)&bL[cur ^ 1][(br_[i] << 5) + (bs_[i] << 3)] = o;
      }
    }
    __syncthreads();
  }

  float bvv[4];
  for (int n = 0; n < 4; ++n) bvv[n] = bias[(bn << 7) + wc + (n << 4) + r16];
  for (int m = 0; m < 4; ++m) {
    int Rbase = (bm << 7) + wr + (m << 4) + (kq << 2);
    for (int r = 0; r < 4; ++r) {
      int R = Rbase + r;
      size_t rowoff;
      if (OUTMODE == 0) {
        rowoff = (size_t)R * N;
      } else {
        int tt = R >> 4, bb = R & 15;
        rowoff = ((size_t)bb * Tdim + tt) * N;
      }
      for (int n = 0; n < 4; ++n)
        C[rowoff + (bn << 7) + wc + (n << 4) + r16] = acc[m][n][r] + bvv[n];
    }
  }
}

// ---------------- fused 2-layer persistent LSTM (wavefront pipelined) ----------------
// Blocks 0..63: layer 0, 16 h-cols each, Whh0 slice in LDS.
// Blocks 64..191: layer 1, 8 h-cols each, Wih1 + Whh1 slices in LDS.
// Step s: L0 computes h0[s]; L1 computes h1[s-1]. Grid barrier = flag-array
// arrive + block-0 aggregation + single go-word broadcast (O(1) poll per block).
__global__ __launch_bounds__(256, 1) void lstm_fused(
    const float* __restrict__ gx,    // [T*16][4096] = xe@Wih0^T + bsum0
    const float* __restrict__ Whh0,  // [4096][1024] f32
    const float* __restrict__ Wih1,  // [4096][1024] f32
    const float* __restrict__ Whh1,  // [4096][1024] f32
    const float* __restrict__ bsum1, // [4096]
    bf16* __restrict__ hs0,          // [T*16][1024]
    bf16* __restrict__ hs1,          // [T*16][1024]
    unsigned* __restrict__ flags,    // [NBLK*FSTR + 64], zeroed
    int T) {
  __shared__ bf16 wlds[64 * 1024];     // 128 KiB, swizzled (chunk ^= row&7)
  __shared__ float glds[4 * 16 * 16];  // gate exchange
  const int tid = threadIdx.x;
  const int l = tid & 63, w = tid >> 6;
  const int bid = blockIdx.x;
  const bool L0 = bid < 64;
  const int r16 = l & 15, kq = l >> 4, rx = r16 & 7;
  unsigned* const go = flags + NBLK * FSTR;

  // ---- stage weight slices to LDS (f32 -> bf16, swizzled) ----
  if (L0) {
    const int j0s = bid << 4;
    for (int it = 0; it < 32; ++it) {
      int lin = tid + (it << 8);
      int row = lin >> 7, cs = lin & 127, c = cs ^ (row & 7);
      int g = row >> 4, n = row & 15;
      const float* src = Whh0 + (size_t)(g * 1024 + j0s + n) * 1024 + (c << 3);
      f32x4 v0 = *(const f32x4*)src;
      f32x4 v1 = *(const f32x4*)(src + 4);
      bf16x8 o;
      for (int j = 0; j < 4; ++j) { o[j] = (bf16)v0[j]; o[j + 4] = (bf16)v1[j]; }
      *(bf16x8*)(wlds + (row << 10) + (cs << 3)) = o;
    }
  } else {
    const int j0s = (bid - 64) << 3;
    for (int it = 0; it < 32; ++it) {
      int lin = tid + (it << 8);
      int row = lin >> 7, cs = lin & 127, c = cs ^ (row & 7);
      int m = row >> 5, rr = row & 31, g = rr >> 3, n = rr & 7;
      const float* W = m ? Whh1 : Wih1;
      const float* src = W + (size_t)(g * 1024 + j0s + n) * 1024 + (c << 3);
      f32x4 v0 = *(const f32x4*)src;
      f32x4 v1 = *(const f32x4*)(src + 4);
      bf16x8 o;
      for (int j = 0; j < 4; ++j) { o[j] = (bf16)v0[j]; o[j + 4] = (bf16)v1[j]; }
      *(bf16x8*)(wlds + (row << 10) + (cs << 3)) = o;
    }
  }
  __syncthreads();

  const int bidx = tid >> 4, jl = tid & 15;  // layer-0 fusion mapping
  const int b1 = tid >> 3, j1 = tid & 7;     // layer-1 fusion mapping (tid<128)
  float cst = 0.f;
  float bi_ = 0.f, bf_ = 0.f, bg_ = 0.f, bo_ = 0.f;
  int j0;
  if (L0) {
    j0 = bid << 4;
  } else {
    j0 = (bid - 64) << 3;
    if (tid < 128) {
      bi_ = bsum1[j0 + j1];
      bf_ = bsum1[1024 + j0 + j1];
      bg_ = bsum1[2048 + j0 + j1];
      bo_ = bsum1[3072 + j0 + j1];
    }
  }
  unsigned* const myflag = flags + (size_t)bid * FSTR;

  for (int s = 0; s <= T; ++s) {
    if (L0) {
      if (s < T) {
        const int t = s;
        const float* gp = gx + ((((size_t)t << 4) + bidx) << 12) + j0 + jl;
        float gi = gp[0], gf = gp[1024], gg2 = gp[2048], go_ = gp[3072];
        f32x4 acc = (f32x4){0.f, 0.f, 0.f, 0.f};
        f32x4 acc2 = (f32x4){0.f, 0.f, 0.f, 0.f};
        if (t > 0) {
          const bf16* hp = hs0 + ((size_t)(t - 1) << 14) + (r16 << 10) + (kq << 3);
          const bf16* wb = wlds + (((w << 4) + r16) << 10);
#pragma unroll 8
          for (int kk = 0; kk < 32; kk += 2) {
            bf16x8 a0 = *(const bf16x8*)(hp + (kk << 5));
            bf16x8 a1 = *(const bf16x8*)(hp + ((kk + 1) << 5));
            acc = __builtin_amdgcn_mfma_f32_16x16x32_bf16(
                a0, *(const bf16x8*)(wb + ((((kk << 2) + kq) ^ rx) << 3)), acc, 0, 0, 0);
            acc2 = __builtin_amdgcn_mfma_f32_16x16x32_bf16(
                a1, *(const bf16x8*)(wb + (((((kk + 1) << 2) + kq) ^ rx) << 3)), acc2, 0, 0, 0);
          }
        }
        for (int r = 0; r < 4; ++r)
          glds[(w << 8) + (((kq << 2) + r) << 4) + r16] = acc[r] + acc2[r];
        __syncthreads();
        float xi = glds[(bidx << 4) + jl] + gi;
        float xf = glds[256 + (bidx << 4) + jl] + gf;
        float xg = glds[512 + (bidx << 4) + jl] + gg2;
        float xo = glds[768 + (bidx << 4) + jl] + go_;
        float ig = 1.f / (1.f + __expf(-xi));
        float fg = 1.f / (1.f + __expf(-xf));
        float eg = __expf(2.f * xg);
        float gg = 1.f - 2.f / (eg + 1.f);
        float og = 1.f / (1.f + __expf(-xo));
        cst = fg * cst + ig * gg;
        float ec = __expf(2.f * cst);
        float th = 1.f - 2.f / (ec + 1.f);
        hs0[((((size_t)t << 4) + bidx) << 10) + j0 + jl] = (bf16)(og * th);
      }
    } else {
      if (s >= 1) {
        const int t1 = s - 1;
        f32x4 acc0 = (f32x4){0.f, 0.f, 0.f, 0.f};
        f32x4 acc1 = (f32x4){0.f, 0.f, 0.f, 0.f};
        const bf16* hp0 = hs0 + ((size_t)t1 << 14) + (r16 << 10) + (kq << 3);
        const bf16* wb0 = wlds + (((w << 3) + rx) << 10);       // Wih1 rows
        const bf16* wb1 = wlds + ((32 + (w << 3) + rx) << 10);  // Whh1 rows
#pragma unroll 8
        for (int kk = 0; kk < 32; ++kk) {
          bf16x8 a0 = *(const bf16x8*)(hp0 + (kk << 5));
          acc0 = __builtin_amdgcn_mfma_f32_16x16x32_bf16(
              a0, *(const bf16x8*)(wb0 + ((((kk << 2) + kq) ^ rx) << 3)), acc0, 0, 0, 0);
        }
        if (t1 > 0) {
          const bf16* hp1 = hs1 + ((size_t)(t1 - 1) << 14) + (r16 << 10) + (kq << 3);
#pragma unroll 8
          for (int kk = 0; kk < 32; ++kk) {
            bf16x8 a1 = *(const bf16x8*)(hp1 + (kk << 5));
            acc1 = __builtin_amdgcn_mfma_f32_16x16x32_bf16(
                a1, *(const bf16x8*)(wb1 + ((((kk << 2) + kq) ^ rx) << 3)), acc1, 0, 0, 0);
          }
        }
        for (int r = 0; r < 4; ++r)
          glds[(w << 8) + (((kq << 2) + r) << 4) + r16] = acc0[r] + acc1[r];
        __syncthreads();
        if (tid < 128) {
          float xi = glds[(b1 << 4) + j1] + bi_;
          float xf = glds[256 + (b1 << 4) + j1] + bf_;
          float xg = glds[512 + (b1 << 4) + j1] + bg_;
          float xo = glds[768 + (b1 << 4) + j1] + bo_;
          float ig = 1.f / (1.f + __expf(-xi));
          float fg = 1.f / (1.f + __expf(-xf));
          float eg = __expf(2.f * xg);
          float gg = 1.f - 2.f / (eg + 1.f);
          float og = 1.f / (1.f + __expf(-xo));
          cst = fg * cst + ig * gg;
          float ec = __expf(2.f * cst);
          float th = 1.f - 2.f / (ec + 1.f);
          hs1[((((size_t)t1 << 4) + b1) << 10) + j0 + j1] = (bf16)(og * th);
        }
      }
    }

    // ---- grid barrier: arrive (own flag) -> block0 aggregates -> go broadcast ----
    if (s < T) {
      const unsigned ep = (unsigned)(s + 1);
      __syncthreads();  // drains vmcnt: all hs stores of this block are in L2
      if (tid == 0)
        __hip_atomic_store(myflag, ep, __ATOMIC_RELEASE, __HIP_MEMORY_SCOPE_AGENT);
      if (bid == 0) {
        if (w < 3) {
          unsigned* fp = flags + (size_t)((w << 6) + l) * FSTR;
          while (__hip_atomic_load(fp, __ATOMIC_RELAXED, __HIP_MEMORY_SCOPE_AGENT) < ep) {
          }
        }
        __syncthreads();  // all 192 flags observed
        if (tid == 0) {
          __threadfence();  // order flag observations + invalidate before go release
          __hip_atomic_store(go, ep, __ATOMIC_RELEASE, __HIP_MEMORY_SCOPE_AGENT);
        }
        __syncthreads();
      } else {
        if (tid == 0) {
          while (__hip_atomic_load(go, __ATOMIC_RELAXED, __HIP_MEMORY_SCOPE_AGENT) < ep)
            __builtin_amdgcn_s_sleep(1);
          (void)__hip_atomic_load(go, __ATOMIC_ACQUIRE, __HIP_MEMORY_SCOPE_AGENT);
        }
        __syncthreads();
      }
    }
  }
}

extern "C" void kernel_launch(void* const* d_in, const int* in_sizes, int n_in,
                              void* d_out, int out_size, void* d_ws, size_t ws_size,
                              hipStream_t stream) {
  const int* x = (const int*)d_in[0];
  const float* emb = (const float*)d_in[1];
  const float* Wih0 = (const float*)d_in[2];
  const float* Whh0 = (const float*)d_in[3];
  const float* bih0 = (const float*)d_in[4];
  const float* bhh0 = (const float*)d_in[5];
  const float* Wih1 = (const float*)d_in[6];
  const float* Whh1 = (const float*)d_in[7];
  const float* bih1 = (const float*)d_in[8];
  const float* bhh1 = (const float*)d_in[9];
  const float* Wout = (const float*)d_in[10];
  const float* bout = (const float*)d_in[11];

  const int T = 512, H = 1024, V = 32000;
  const int M = T * 16;
  const size_t bfb = (size_t)M * H * 2;  // 16 MiB bf16 plane

  char* p = (char*)d_ws;
  bf16* hs1 = (bf16*)p;           p += bfb;  // must survive into projection -> ws
  float* bsum0 = (float*)p;       p += 4096 * 4;
  float* bsum1 = (float*)p;       p += 4096 * 4;
  unsigned* flags = (unsigned*)p; p += (NBLK * FSTR + 64) * 4;
  size_t base_need = (size_t)(p - (char*)d_ws);
  bf16 *xe, *hs0;
  if (ws_size >= base_need + 2 * bfb) {
    xe = (bf16*)p;
    hs0 = (bf16*)(p + bfb);
  } else {  // d_out tail is dead until projection overwrites it
    char* tail = (char*)d_out + (size_t)out_size * 4 - 2 * bfb;
    xe = (bf16*)tail;
    hs0 = (bf16*)(tail + bfb);
  }
  float* gx = (float*)d_out;  // 134 MB scratch at head of d_out

  init_misc<<<32, 256, 0, stream>>>(bih0, bhh0, bih1, bhh1, bsum0, bsum1, flags);
  embed_gather<<<M, 256, 0, stream>>>(x, emb, xe, T);
  gemm_bf16<0><<<(M / 128) * (4096 / 128), 256, 0, stream>>>(xe, Wih0, bsum0, gx, M, 4096, H, 0);
  lstm_fused<<<NBLK, 256, 0, stream>>>(gx, Whh0, Wih1, Whh1, bsum1, hs0, hs1, flags, T);
  gemm_bf16<1><<<(M / 128) * (V / 128), 256, 0, stream>>>(hs1, Wout, bout, (float*)d_out, M, V, H, T);
}

// Round 4
// 6183.415 us; speedup vs baseline: 2.8520x; 1.1904x over previous
//
#include <hip/hip_runtime.h>
#include <cstdint>
#include <cstddef>

typedef __bf16 bf16;
typedef float f32x4 __attribute__((ext_vector_type(4)));
typedef bf16 bf16x8 __attribute__((ext_vector_type(8)));
typedef bf16 bf16x4 __attribute__((ext_vector_type(4)));

#define AS1 __attribute__((address_space(1)))
#define AS3 __attribute__((address_space(3)))

__device__ __forceinline__ void gload_lds16(const void* g, void* l) {
  __builtin_amdgcn_global_load_lds((AS1 void*)g, (AS3 void*)l, 16, 0, 0);
}

#define NBLK_W 192  // worker blocks (64 L0 + 128 L1); +1 aggregator
#define FSTR 32     // flag stride in unsigned (128B)
// flags layout: flag0[64] | flag1[128] | mbA[192] | mbB[128]  (each * FSTR u32)
#define FLAG_WORDS ((64 + 128 + 192 + 128) * FSTR)

// ---------------- init: combined biases + flags ----------------
__global__ __launch_bounds__(256) void init_misc(
    const float* __restrict__ bih0, const float* __restrict__ bhh0,
    const float* __restrict__ bih1, const float* __restrict__ bhh1,
    float* __restrict__ bsum0, float* __restrict__ bsum1, unsigned* __restrict__ flags) {
  int i = blockIdx.x * 256 + threadIdx.x;
  if (i < 4096) {
    bsum0[i] = bih0[i] + bhh0[i];
    bsum1[i] = bih1[i] + bhh1[i];
  }
  if (i < FLAG_WORDS) flags[i] = 0u;
}

// ---------------- embedding gather -> bf16, row = t*16 + b ----------------
__global__ __launch_bounds__(256) void embed_gather(
    const int* __restrict__ x, const float* __restrict__ emb, bf16* __restrict__ xe, int T) {
  int row = blockIdx.x;  // t*16 + b
  int t = row >> 4, b = row & 15;
  int tok = x[b * T + t];
  int cix = threadIdx.x << 2;
  f32x4 v = *(const f32x4*)(emb + ((size_t)tok << 10) + cix);
  bf16x4 o;
  for (int j = 0; j < 4; ++j) o[j] = (bf16)v[j];
  *(bf16x4*)(xe + ((size_t)row << 10) + cix) = o;
}

// ---------------- GEMM: C[M,N] = A[M,K](bf16) * W[N,K](f32->bf16)^T + bias ----------------
template <int OUTMODE>
__global__ __launch_bounds__(256) void gemm_bf16(
    const bf16* __restrict__ A, const float* __restrict__ Bw,
    const float* __restrict__ bias, float* __restrict__ C,
    int M, int N, int K, int Tdim) {
  __shared__ bf16 aL[2][128 * 32];
  __shared__ bf16 bL[2][128 * 32];
  const int tid = threadIdx.x;
  const int l = tid & 63, w = tid >> 6;
  const int nbm = M >> 7;
  const int bm = blockIdx.x % nbm;
  const int bn = blockIdx.x / nbm;
  const int wr = (w >> 1) << 6, wc = (w & 1) << 6;
  const int NT = K >> 5;
  const int r16 = l & 15, kq = l >> 4;

  f32x4 acc[4][4];
  for (int m = 0; m < 4; ++m)
    for (int n = 0; n < 4; ++n) acc[m][n] = (f32x4){0.f, 0.f, 0.f, 0.f};

  for (int i = 0; i < 2; ++i) {
    int lin = tid + (i << 8);
    int r = lin >> 2, s = lin & 3, c = s ^ (r & 3);
    gload_lds16(A + (size_t)((bm << 7) + r) * K + (c << 3), &aL[0][lin << 3]);
  }
  for (int i = 0; i < 2; ++i) {
    int lin = tid + (i << 8);
    int r = lin >> 2, c = lin & 3;
    const float* src = Bw + (size_t)((bn << 7) + r) * K + (c << 3);
    f32x4 v0 = *(const f32x4*)src;
    f32x4 v1 = *(const f32x4*)(src + 4);
    bf16x8 o;
    for (int j = 0; j < 4; ++j) { o[j] = (bf16)v0[j]; o[j + 4] = (bf16)v1[j]; }
    *(bf16x8*)&bL[0][(r << 5) + ((c ^ (r & 3)) << 3)] = o;
  }
  __syncthreads();

  for (int kt = 0; kt < NT; ++kt) {
    const int cur = kt & 1;
    const bool pf = (kt + 1 < NT);
    f32x4 bv0[2], bv1[2];
    int br_[2], bs_[2];
    if (pf) {
      for (int i = 0; i < 2; ++i) {
        int lin = tid + (i << 8);
        int r = lin >> 2, s = lin & 3, c = s ^ (r & 3);
        gload_lds16(A + (size_t)((bm << 7) + r) * K + ((kt + 1) << 5) + (c << 3),
                    &aL[cur ^ 1][lin << 3]);
      }
      for (int i = 0; i < 2; ++i) {
        int lin = tid + (i << 8);
        int r = lin >> 2, c = lin & 3;
        const float* src = Bw + (size_t)((bn << 7) + r) * K + ((kt + 1) << 5) + (c << 3);
        bv0[i] = *(const f32x4*)src;
        bv1[i] = *(const f32x4*)(src + 4);
        br_[i] = r;
        bs_[i] = c ^ (r & 3);
      }
    }
    bf16x8 af[4], bfr[4];
    for (int m = 0; m < 4; ++m) {
      int row = wr + (m << 4) + r16;
      int ch = kq ^ (row & 3);
      af[m] = *(const bf16x8*)&aL[cur][(row << 5) + (ch << 3)];
    }
    for (int n = 0; n < 4; ++n) {
      int row = wc + (n << 4) + r16;
      int ch = kq ^ (row & 3);
      bfr[n] = *(const bf16x8*)&bL[cur][(row << 5) + (ch << 3)];
    }
    for (int m = 0; m < 4; ++m)
      for (int n = 0; n < 4; ++n)
        acc[m][n] = __builtin_amdgcn_mfma_f32_16x16x32_bf16(af[m], bfr[n], acc[m][n], 0, 0, 0);
    if (pf) {
      for (int i = 0; i < 2; ++i) {
        bf16x8 o;
        for (int j = 0; j < 4; ++j) { o[j] = (bf16)bv0[i][j]; o[j + 4] = (bf16)bv1[i][j]; }
        *(bf16x8*)&bL[cur ^ 1][(br_[i] << 5) + (bs_[i] << 3)] = o;
      }
    }
    __syncthreads();
  }

  float bvv[4];
  for (int n = 0; n < 4; ++n) bvv[n] = bias[(bn << 7) + wc + (n << 4) + r16];
  for (int m = 0; m < 4; ++m) {
    int Rbase = (bm << 7) + wr + (m << 4) + (kq << 2);
    for (int r = 0; r < 4; ++r) {
      int R = Rbase + r;
      size_t rowoff;
      if (OUTMODE == 0) {
        rowoff = (size_t)R * N;
      } else {
        int tt = R >> 4, bb = R & 15;
        rowoff = ((size_t)bb * Tdim + tt) * N;
      }
      for (int n = 0; n < 4; ++n)
        C[rowoff + (bn << 7) + wc + (n << 4) + r16] = acc[m][n][r] + bvv[n];
    }
  }
}

// ---------------- dependency-pipelined 2-layer persistent LSTM ----------------
// Workers: bid 0..63 = layer 0 (16 cols), bid 64..191 = layer 1 (8 cols).
// Block NBLK_W = aggregator: wave0 condenses 64 L0 flags -> mbA[0..191];
// wave1 condenses 128 L1 flags -> mbB[0..127]. Every flag/mailbox line has
// exactly 1 writer + 1 poller (zero contention). Data stores are write-through
// (sc1 nt) so no L2 writeback/invalidate is ever needed.
__global__ __launch_bounds__(256, 1) void lstm_pipe(
    const float* __restrict__ gx,     // [T*16][4096] = xe@Wih0^T + bsum0
    const float* __restrict__ Whh0,   // [4096][1024] f32
    const float* __restrict__ Wih1,   // [4096][1024] f32
    const float* __restrict__ Whh1,   // [4096][1024] f32
    const float* __restrict__ bsum1,  // [4096]
    bf16* __restrict__ hs0,           // [T*16][1024]
    bf16* __restrict__ hs1,           // [T*16][1024]
    unsigned* __restrict__ flags,     // FLAG_WORDS, zeroed
    int T) {
  __shared__ bf16 wlds[64 * 1024];     // 128 KiB, swizzled (chunk ^= row&7)
  __shared__ float glds[4 * 16 * 16];  // gate exchange
  const int tid = threadIdx.x;
  const int l = tid & 63, w = tid >> 6;
  const int bid = blockIdx.x;
  unsigned* const flag0 = flags;
  unsigned* const flag1 = flags + 64 * FSTR;
  unsigned* const mbA = flags + 192 * FSTR;
  unsigned* const mbB = flags + 384 * FSTR;

  // ================= aggregator block =================
  if (bid == NBLK_W) {
    if (w == 0) {
      unsigned* fp = flag0 + (size_t)l * FSTR;
      unsigned* m0 = mbA + (size_t)l * FSTR;
      unsigned* m1 = mbA + (size_t)(l + 64) * FSTR;
      unsigned* m2 = mbA + (size_t)(l + 128) * FSTR;
      for (int e = 1; e <= T; ++e) {
        while (__hip_atomic_load(fp, __ATOMIC_RELAXED, __HIP_MEMORY_SCOPE_AGENT) < (unsigned)e) {
        }
        __hip_atomic_store(m0, (unsigned)e, __ATOMIC_RELAXED, __HIP_MEMORY_SCOPE_AGENT);
        __hip_atomic_store(m1, (unsigned)e, __ATOMIC_RELAXED, __HIP_MEMORY_SCOPE_AGENT);
        __hip_atomic_store(m2, (unsigned)e, __ATOMIC_RELAXED, __HIP_MEMORY_SCOPE_AGENT);
      }
    } else if (w == 1) {
      unsigned* fa = flag1 + (size_t)l * FSTR;
      unsigned* fb = flag1 + (size_t)(l + 64) * FSTR;
      unsigned* m0 = mbB + (size_t)l * FSTR;
      unsigned* m1 = mbB + (size_t)(l + 64) * FSTR;
      for (int e = 1; e <= T - 1; ++e) {
        while (__hip_atomic_load(fa, __ATOMIC_RELAXED, __HIP_MEMORY_SCOPE_AGENT) < (unsigned)e) {
        }
        while (__hip_atomic_load(fb, __ATOMIC_RELAXED, __HIP_MEMORY_SCOPE_AGENT) < (unsigned)e) {
        }
        __hip_atomic_store(m0, (unsigned)e, __ATOMIC_RELAXED, __HIP_MEMORY_SCOPE_AGENT);
        __hip_atomic_store(m1, (unsigned)e, __ATOMIC_RELAXED, __HIP_MEMORY_SCOPE_AGENT);
      }
    }
    return;
  }

  // ================= worker blocks =================
  const bool L0 = bid < 64;
  const int r16 = l & 15, kq = l >> 4, rx = r16 & 7;

  // ---- stage weight slices to LDS (f32 -> bf16, swizzled) ----
  if (L0) {
    const int j0s = bid << 4;
    for (int it = 0; it < 32; ++it) {
      int lin = tid + (it << 8);
      int row = lin >> 7, cs = lin & 127, c = cs ^ (row & 7);
      int g = row >> 4, n = row & 15;
      const float* src = Whh0 + (size_t)(g * 1024 + j0s + n) * 1024 + (c << 3);
      f32x4 v0 = *(const f32x4*)src;
      f32x4 v1 = *(const f32x4*)(src + 4);
      bf16x8 o;
      for (int j = 0; j < 4; ++j) { o[j] = (bf16)v0[j]; o[j + 4] = (bf16)v1[j]; }
      *(bf16x8*)(wlds + (row << 10) + (cs << 3)) = o;
    }
  } else {
    const int j0s = (bid - 64) << 3;
    for (int it = 0; it < 32; ++it) {
      int lin = tid + (it << 8);
      int row = lin >> 7, cs = lin & 127, c = cs ^ (row & 7);
      int m = row >> 5, rr = row & 31, g = rr >> 3, n = rr & 7;
      const float* W = m ? Whh1 : Wih1;
      const float* src = W + (size_t)(g * 1024 + j0s + n) * 1024 + (c << 3);
      f32x4 v0 = *(const f32x4*)src;
      f32x4 v1 = *(const f32x4*)(src + 4);
      bf16x8 o;
      for (int j = 0; j < 4; ++j) { o[j] = (bf16)v0[j]; o[j + 4] = (bf16)v1[j]; }
      *(bf16x8*)(wlds + (row << 10) + (cs << 3)) = o;
    }
  }
  __syncthreads();

  if (L0) {
    const int j0 = bid << 4;
    const int bidx = tid >> 4, jl = tid & 15;
    unsigned* const myflag = flag0 + (size_t)bid * FSTR;
    unsigned* const mymb = mbA + (size_t)bid * FSTR;
    float cst = 0.f;

    for (int t = 0; t < T; ++t) {
      // prefetch gx for this step (overlaps the mailbox wait)
      const float* gp = gx + ((((size_t)t << 4) + bidx) << 12) + j0 + jl;
      float gi = gp[0], gf = gp[1024], gg2 = gp[2048], go_ = gp[3072];
      // wait: h0[t-1] complete (all 64 L0 flags >= t, condensed into mbA)
      if (t > 0 && tid == 0) {
        while (__hip_atomic_load(mymb, __ATOMIC_RELAXED, __HIP_MEMORY_SCOPE_AGENT) < (unsigned)t) {
        }
      }
      __syncthreads();
      asm volatile("" ::: "memory");

      f32x4 acc = (f32x4){0.f, 0.f, 0.f, 0.f};
      f32x4 acc2 = (f32x4){0.f, 0.f, 0.f, 0.f};
      if (t > 0) {
        const bf16* hp = hs0 + ((size_t)(t - 1) << 14) + (r16 << 10) + (kq << 3);
        const bf16* wb = wlds + (((w << 4) + r16) << 10);
#pragma unroll 8
        for (int kk = 0; kk < 32; kk += 2) {
          bf16x8 a0 = *(const bf16x8*)(hp + (kk << 5));
          bf16x8 a1 = *(const bf16x8*)(hp + ((kk + 1) << 5));
          acc = __builtin_amdgcn_mfma_f32_16x16x32_bf16(
              a0, *(const bf16x8*)(wb + ((((kk << 2) + kq) ^ rx) << 3)), acc, 0, 0, 0);
          acc2 = __builtin_amdgcn_mfma_f32_16x16x32_bf16(
              a1, *(const bf16x8*)(wb + (((((kk + 1) << 2) + kq) ^ rx) << 3)), acc2, 0, 0, 0);
        }
      }
      for (int r = 0; r < 4; ++r)
        glds[(w << 8) + (((kq << 2) + r) << 4) + r16] = acc[r] + acc2[r];
      __syncthreads();

      float xi = glds[(bidx << 4) + jl] + gi;
      float xf = glds[256 + (bidx << 4) + jl] + gf;
      float xg = glds[512 + (bidx << 4) + jl] + gg2;
      float xo = glds[768 + (bidx << 4) + jl] + go_;
      float ig = 1.f / (1.f + __expf(-xi));
      float fg = 1.f / (1.f + __expf(-xf));
      float eg = __expf(2.f * xg);
      float ggv = 1.f - 2.f / (eg + 1.f);
      float og = 1.f / (1.f + __expf(-xo));
      cst = fg * cst + ig * ggv;
      float ec = __expf(2.f * cst);
      float th = 1.f - 2.f / (ec + 1.f);
      bf16 hb = (bf16)(og * th);
      unsigned hu = (unsigned)__builtin_bit_cast(unsigned short, hb);
      unsigned other = (unsigned)__shfl_xor((int)hu, 1, 64);
      if (!(tid & 1)) {
        unsigned pair = (hu & 0xffffu) | (other << 16);
        bf16* sp = hs0 + ((((size_t)t << 4) + bidx) << 10) + j0 + jl;
        asm volatile("global_store_dword %0, %1, off sc1 nt" ::"v"(sp), "v"(pair) : "memory");
      }
      asm volatile("s_waitcnt vmcnt(0)" ::: "memory");
      __syncthreads();  // all waves' write-through stores MALL-acked
      if (tid == 0)
        __hip_atomic_store(myflag, (unsigned)(t + 1), __ATOMIC_RELAXED, __HIP_MEMORY_SCOPE_AGENT);
    }
  } else {
    const int j0 = (bid - 64) << 3;
    const int b1 = tid >> 3, j1 = tid & 7;
    unsigned* const myflag = flag1 + (size_t)(bid - 64) * FSTR;
    unsigned* const mbAp = mbA + (size_t)bid * FSTR;
    unsigned* const mbBp = mbB + (size_t)(bid - 64) * FSTR;
    float cst = 0.f;
    float bi_ = 0.f, bf_ = 0.f, bg_ = 0.f, bo_ = 0.f;
    if (tid < 128) {
      bi_ = bsum1[j0 + j1];
      bf_ = bsum1[1024 + j0 + j1];
      bg_ = bsum1[2048 + j0 + j1];
      bo_ = bsum1[3072 + j0 + j1];
    }

    for (int t1 = 0; t1 < T; ++t1) {
      // wait: h0[t1] ready (mbA >= t1+1) and h1[t1-1] ready (mbB >= t1)
      if (tid < 2) {
        unsigned tgt = (tid == 0) ? (unsigned)(t1 + 1) : (unsigned)t1;
        unsigned* wp = (tid == 0) ? mbAp : mbBp;
        while (tgt &&
               __hip_atomic_load(wp, __ATOMIC_RELAXED, __HIP_MEMORY_SCOPE_AGENT) < tgt) {
        }
      }
      __syncthreads();
      asm volatile("" ::: "memory");

      f32x4 acc0 = (f32x4){0.f, 0.f, 0.f, 0.f};
      f32x4 acc1 = (f32x4){0.f, 0.f, 0.f, 0.f};
      const bf16* hp0 = hs0 + ((size_t)t1 << 14) + (r16 << 10) + (kq << 3);
      const bf16* wb0 = wlds + (((w << 3) + rx) << 10);       // Wih1 rows
      const bf16* wb1 = wlds + ((32 + (w << 3) + rx) << 10);  // Whh1 rows
#pragma unroll 8
      for (int kk = 0; kk < 32; ++kk) {
        bf16x8 a0 = *(const bf16x8*)(hp0 + (kk << 5));
        acc0 = __builtin_amdgcn_mfma_f32_16x16x32_bf16(
            a0, *(const bf16x8*)(wb0 + ((((kk << 2) + kq) ^ rx) << 3)), acc0, 0, 0, 0);
      }
      if (t1 > 0) {
        const bf16* hp1 = hs1 + ((size_t)(t1 - 1) << 14) + (r16 << 10) + (kq << 3);
#pragma unroll 8
        for (int kk = 0; kk < 32; ++kk) {
          bf16x8 a1 = *(const bf16x8*)(hp1 + (kk << 5));
          acc1 = __builtin_amdgcn_mfma_f32_16x16x32_bf16(
              a1, *(const bf16x8*)(wb1 + ((((kk << 2) + kq) ^ rx) << 3)), acc1, 0, 0, 0);
        }
      }
      for (int r = 0; r < 4; ++r)
        glds[(w << 8) + (((kq << 2) + r) << 4) + r16] = acc0[r] + acc1[r];
      __syncthreads();

      if (tid < 128) {
        float xi = glds[(b1 << 4) + j1] + bi_;
        float xf = glds[256 + (b1 << 4) + j1] + bf_;
        float xg = glds[512 + (b1 << 4) + j1] + bg_;
        float xo = glds[768 + (b1 << 4) + j1] + bo_;
        float ig = 1.f / (1.f + __expf(-xi));
        float fg = 1.f / (1.f + __expf(-xf));
        float eg = __expf(2.f * xg);
        float ggv = 1.f - 2.f / (eg + 1.f);
        float og = 1.f / (1.f + __expf(-xo));
        cst = fg * cst + ig * ggv;
        float ec = __expf(2.f * cst);
        float th = 1.f - 2.f / (ec + 1.f);
        bf16 hb = (bf16)(og * th);
        unsigned hu = (unsigned)__builtin_bit_cast(unsigned short, hb);
        unsigned other = (unsigned)__shfl_xor((int)hu, 1, 64);
        if (!(tid & 1)) {
          unsigned pair = (hu & 0xffffu) | (other << 16);
          bf16* sp = hs1 + ((((size_t)t1 << 4) + b1) << 10) + j0 + j1;
          asm volatile("global_store_dword %0, %1, off sc1 nt" ::"v"(sp), "v"(pair) : "memory");
        }
      }
      asm volatile("s_waitcnt vmcnt(0)" ::: "memory");
      __syncthreads();
      if (tid == 0)
        __hip_atomic_store(myflag, (unsigned)(t1 + 1), __ATOMIC_RELAXED, __HIP_MEMORY_SCOPE_AGENT);
    }
  }
}

extern "C" void kernel_launch(void* const* d_in, const int* in_sizes, int n_in,
                              void* d_out, int out_size, void* d_ws, size_t ws_size,
                              hipStream_t stream) {
  const int* x = (const int*)d_in[0];
  const float* emb = (const float*)d_in[1];
  const float* Wih0 = (const float*)d_in[2];
  const float* Whh0 = (const float*)d_in[3];
  const float* bih0 = (const float*)d_in[4];
  const float* bhh0 = (const float*)d_in[5];
  const float* Wih1 = (const float*)d_in[6];
  const float* Whh1 = (const float*)d_in[7];
  const float* bih1 = (const float*)d_in[8];
  const float* bhh1 = (const float*)d_in[9];
  const float* Wout = (const float*)d_in[10];
  const float* bout = (const float*)d_in[11];

  const int T = 512, H = 1024, V = 32000;
  const int M = T * 16;
  const size_t bfb = (size_t)M * H * 2;  // 16 MiB bf16 plane

  char* p = (char*)d_ws;
  bf16* hs1 = (bf16*)p;           p += bfb;  // must survive into projection -> ws
  float* bsum0 = (float*)p;       p += 4096 * 4;
  float* bsum1 = (float*)p;       p += 4096 * 4;
  unsigned* flags = (unsigned*)p; p += FLAG_WORDS * 4;
  size_t base_need = (size_t)(p - (char*)d_ws);
  bf16 *xe, *hs0;
  if (ws_size >= base_need + 2 * bfb) {
    xe = (bf16*)p;
    hs0 = (bf16*)(p + bfb);
  } else {  // d_out tail is dead until projection overwrites it
    char* tail = (char*)d_out + (size_t)out_size * 4 - 2 * bfb;
    xe = (bf16*)tail;
    hs0 = (bf16*)(tail + bfb);
  }
  float* gx = (float*)d_out;  // 134 MB scratch at head of d_out

  init_misc<<<64, 256, 0, stream>>>(bih0, bhh0, bih1, bhh1, bsum0, bsum1, flags);
  embed_gather<<<M, 256, 0, stream>>>(x, emb, xe, T);
  gemm_bf16<0><<<(M / 128) * (4096 / 128), 256, 0, stream>>>(xe, Wih0, bsum0, gx, M, 4096, H, 0);
  lstm_pipe<<<NBLK_W + 1, 256, 0, stream>>>(gx, Whh0, Wih1, Whh1, bsum1, hs0, hs1, flags, T);
  gemm_bf16<1><<<(M / 128) * (V / 128), 256, 0, stream>>>(hs1, Wout, bout, (float*)d_out, M, V, H, T);
}

// Round 5
// 5997.381 us; speedup vs baseline: 2.9405x; 1.0310x over previous
//
#include <hip/hip_runtime.h>
#include <cstdint>
#include <cstddef>

typedef __bf16 bf16;
typedef float f32x4 __attribute__((ext_vector_type(4)));
typedef bf16 bf16x8 __attribute__((ext_vector_type(8)));
typedef bf16 bf16x4 __attribute__((ext_vector_type(4)));

#define AS1 __attribute__((address_space(1)))
#define AS3 __attribute__((address_space(3)))

__device__ __forceinline__ void gload_lds16(const void* g, void* l) {
  __builtin_amdgcn_global_load_lds((AS1 void*)g, (AS3 void*)l, 16, 0, 0);
}

#define NBLK_W 192  // 64 L0 + 128 L1 worker blocks
// direct-signal flag matrices (4B words, consumer-major rows)
#define D0_WORDS (64 * 64)     // done0[c][p]  : L0 -> L0
#define D01_WORDS (128 * 64)   // done01[c][p] : L0 -> L1
#define D1_WORDS (128 * 128)   // done1[c][p]  : L1 -> L1
#define FLAG_WORDS (D0_WORDS + D01_WORDS + D1_WORDS)

// ---------------- init: combined biases + flags ----------------
__global__ __launch_bounds__(256) void init_misc(
    const float* __restrict__ bih0, const float* __restrict__ bhh0,
    const float* __restrict__ bih1, const float* __restrict__ bhh1,
    float* __restrict__ bsum0, float* __restrict__ bsum1, unsigned* __restrict__ flags) {
  int i = blockIdx.x * 256 + threadIdx.x;
  if (i < 4096) {
    bsum0[i] = bih0[i] + bhh0[i];
    bsum1[i] = bih1[i] + bhh1[i];
  }
  for (int k = i; k < FLAG_WORDS; k += 64 * 256) flags[k] = 0u;
}

// ---------------- embedding gather -> bf16, row = t*16 + b ----------------
__global__ __launch_bounds__(256) void embed_gather(
    const int* __restrict__ x, const float* __restrict__ emb, bf16* __restrict__ xe, int T) {
  int row = blockIdx.x;  // t*16 + b
  int t = row >> 4, b = row & 15;
  int tok = x[b * T + t];
  int cix = threadIdx.x << 2;
  f32x4 v = *(const f32x4*)(emb + ((size_t)tok << 10) + cix);
  bf16x4 o;
  for (int j = 0; j < 4; ++j) o[j] = (bf16)v[j];
  *(bf16x4*)(xe + ((size_t)row << 10) + cix) = o;
}

// ---------------- GEMM: C[M,N] = A[M,K](bf16) * W[N,K](f32->bf16)^T + bias ----------------
template <int OUTMODE>
__global__ __launch_bounds__(256) void gemm_bf16(
    const bf16* __restrict__ A, const float* __restrict__ Bw,
    const float* __restrict__ bias, float* __restrict__ C,
    int M, int N, int K, int Tdim) {
  __shared__ bf16 aL[2][128 * 32];
  __shared__ bf16 bL[2][128 * 32];
  const int tid = threadIdx.x;
  const int l = tid & 63, w = tid >> 6;
  const int nbm = M >> 7;
  const int bm = blockIdx.x % nbm;
  const int bn = blockIdx.x / nbm;
  const int wr = (w >> 1) << 6, wc = (w & 1) << 6;
  const int NT = K >> 5;
  const int r16 = l & 15, kq = l >> 4;

  f32x4 acc[4][4];
  for (int m = 0; m < 4; ++m)
    for (int n = 0; n < 4; ++n) acc[m][n] = (f32x4){0.f, 0.f, 0.f, 0.f};

  for (int i = 0; i < 2; ++i) {
    int lin = tid + (i << 8);
    int r = lin >> 2, s = lin & 3, c = s ^ (r & 3);
    gload_lds16(A + (size_t)((bm << 7) + r) * K + (c << 3), &aL[0][lin << 3]);
  }
  for (int i = 0; i < 2; ++i) {
    int lin = tid + (i << 8);
    int r = lin >> 2, c = lin & 3;
    const float* src = Bw + (size_t)((bn << 7) + r) * K + (c << 3);
    f32x4 v0 = *(const f32x4*)src;
    f32x4 v1 = *(const f32x4*)(src + 4);
    bf16x8 o;
    for (int j = 0; j < 4; ++j) { o[j] = (bf16)v0[j]; o[j + 4] = (bf16)v1[j]; }
    *(bf16x8*)&bL[0][(r << 5) + ((c ^ (r & 3)) << 3)] = o;
  }
  __syncthreads();

  for (int kt = 0; kt < NT; ++kt) {
    const int cur = kt & 1;
    const bool pf = (kt + 1 < NT);
    f32x4 bv0[2], bv1[2];
    int br_[2], bs_[2];
    if (pf) {
      for (int i = 0; i < 2; ++i) {
        int lin = tid + (i << 8);
        int r = lin >> 2, s = lin & 3, c = s ^ (r & 3);
        gload_lds16(A + (size_t)((bm << 7) + r) * K + ((kt + 1) << 5) + (c << 3),
                    &aL[cur ^ 1][lin << 3]);
      }
      for (int i = 0; i < 2; ++i) {
        int lin = tid + (i << 8);
        int r = lin >> 2, c = lin & 3;
        const float* src = Bw + (size_t)((bn << 7) + r) * K + ((kt + 1) << 5) + (c << 3);
        bv0[i] = *(const f32x4*)src;
        bv1[i] = *(const f32x4*)(src + 4);
        br_[i] = r;
        bs_[i] = c ^ (r & 3);
      }
    }
    bf16x8 af[4], bfr[4];
    for (int m = 0; m < 4; ++m) {
      int row = wr + (m << 4) + r16;
      int ch = kq ^ (row & 3);
      af[m] = *(const bf16x8*)&aL[cur][(row << 5) + (ch << 3)];
    }
    for (int n = 0; n < 4; ++n) {
      int row = wc + (n << 4) + r16;
      int ch = kq ^ (row & 3);
      bfr[n] = *(const bf16x8*)&bL[cur][(row << 5) + (ch << 3)];
    }
    for (int m = 0; m < 4; ++m)
      for (int n = 0; n < 4; ++n)
        acc[m][n] = __builtin_amdgcn_mfma_f32_16x16x32_bf16(af[m], bfr[n], acc[m][n], 0, 0, 0);
    if (pf) {
      for (int i = 0; i < 2; ++i) {
        bf16x8 o;
        for (int j = 0; j < 4; ++j) { o[j] = (bf16)bv0[i][j]; o[j + 4] = (bf16)bv1[i][j]; }
        *(bf16x8*)&bL[cur ^ 1][(br_[i] << 5) + (bs_[i] << 3)] = o;
      }
    }
    __syncthreads();
  }

  float bvv[4];
  for (int n = 0; n < 4; ++n) bvv[n] = bias[(bn << 7) + wc + (n << 4) + r16];
  for (int m = 0; m < 4; ++m) {
    int Rbase = (bm << 7) + wr + (m << 4) + (kq << 2);
    for (int r = 0; r < 4; ++r) {
      int R = Rbase + r;
      size_t rowoff;
      if (OUTMODE == 0) {
        rowoff = (size_t)R * N;
      } else {
        int tt = R >> 4, bb = R & 15;
        rowoff = ((size_t)bb * Tdim + tt) * N;
      }
      for (int n = 0; n < 4; ++n)
        C[rowoff + (bn << 7) + wc + (n << 4) + r16] = acc[m][n][r] + bvv[n];
    }
  }
}

// ---------------- direct-signal pipelined 2-layer persistent LSTM ----------------
// bid 0..63 = layer 0 (16 cols), bid 64..191 = layer 1 (8 cols).
// Producer->consumer signaling is a dense flag matrix: after ONE vmcnt drain,
// lane l of waves 0..2 stores the epoch straight into consumer l's flag row.
// Consumer waits with one wave polling its own 64-flag row (2 cachelines).
// Every flag word has exactly 1 writer and 1 poller; no aggregator hops.
__global__ __launch_bounds__(256, 1) void lstm_pipe(
    const float* __restrict__ gx,     // [T*16][4096] = xe@Wih0^T + bsum0
    const float* __restrict__ Whh0,   // [4096][1024] f32
    const float* __restrict__ Wih1,   // [4096][1024] f32
    const float* __restrict__ Whh1,   // [4096][1024] f32
    const float* __restrict__ bsum1,  // [4096]
    bf16* __restrict__ hs0,           // [T*16][1024]
    bf16* __restrict__ hs1,           // [T*16][1024]
    unsigned* __restrict__ flags,     // FLAG_WORDS, zeroed
    int T) {
  __shared__ bf16 wlds[64 * 1024];     // 128 KiB, swizzled (chunk ^= row&7)
  __shared__ float glds[4 * 16 * 16];  // gate exchange
  const int tid = threadIdx.x;
  const int l = tid & 63, w = tid >> 6;
  const int bid = blockIdx.x;
  unsigned* const done0 = flags;                    // [64][64]
  unsigned* const done01 = flags + D0_WORDS;        // [128][64]
  unsigned* const done1 = flags + D0_WORDS + D01_WORDS;  // [128][128]

  const bool L0 = bid < 64;
  const int r16 = l & 15, kq = l >> 4, rx = r16 & 7;

  // ---- stage weight slices to LDS (f32 -> bf16, swizzled) ----
  if (L0) {
    const int j0s = bid << 4;
    for (int it = 0; it < 32; ++it) {
      int lin = tid + (it << 8);
      int row = lin >> 7, cs = lin & 127, c = cs ^ (row & 7);
      int g = row >> 4, n = row & 15;
      const float* src = Whh0 + (size_t)(g * 1024 + j0s + n) * 1024 + (c << 3);
      f32x4 v0 = *(const f32x4*)src;
      f32x4 v1 = *(const f32x4*)(src + 4);
      bf16x8 o;
      for (int j = 0; j < 4; ++j) { o[j] = (bf16)v0[j]; o[j + 4] = (bf16)v1[j]; }
      *(bf16x8*)(wlds + (row << 10) + (cs << 3)) = o;
    }
  } else {
    const int j0s = (bid - 64) << 3;
    for (int it = 0; it < 32; ++it) {
      int lin = tid + (it << 8);
      int row = lin >> 7, cs = lin & 127, c = cs ^ (row & 7);
      int m = row >> 5, rr = row & 31, g = rr >> 3, n = rr & 7;
      const float* W = m ? Whh1 : Wih1;
      const float* src = W + (size_t)(g * 1024 + j0s + n) * 1024 + (c << 3);
      f32x4 v0 = *(const f32x4*)src;
      f32x4 v1 = *(const f32x4*)(src + 4);
      bf16x8 o;
      for (int j = 0; j < 4; ++j) { o[j] = (bf16)v0[j]; o[j + 4] = (bf16)v1[j]; }
      *(bf16x8*)(wlds + (row << 10) + (cs << 3)) = o;
    }
  }
  __syncthreads();

  if (L0) {
    const int j0 = bid << 4;
    const int bidx = tid >> 4, jl = tid & 15;
    float cst = 0.f;

    for (int t = 0; t < T; ++t) {
      // prefetch gx for this step (overlaps the flag wait)
      const float* gp = gx + ((((size_t)t << 4) + bidx) << 12) + j0 + jl;
      float gi = gp[0], gf = gp[1024], gg2 = gp[2048], go_ = gp[3072];
      // wait: all 64 L0 producers at epoch >= t (h0[t-1] complete)
      if (t > 0 && w == 0) {
        const unsigned* fp = done0 + (bid << 6) + l;
        while (__hip_atomic_load(fp, __ATOMIC_RELAXED, __HIP_MEMORY_SCOPE_AGENT) <
               (unsigned)t) {
        }
      }
      __syncthreads();
      asm volatile("" ::: "memory");

      f32x4 acc = (f32x4){0.f, 0.f, 0.f, 0.f};
      f32x4 acc2 = (f32x4){0.f, 0.f, 0.f, 0.f};
      if (t > 0) {
        const bf16* hp = hs0 + ((size_t)(t - 1) << 14) + (r16 << 10) + (kq << 3);
        const bf16* wb = wlds + (((w << 4) + r16) << 10);
#pragma unroll 8
        for (int kk = 0; kk < 32; kk += 2) {
          bf16x8 a0 = *(const bf16x8*)(hp + (kk << 5));
          bf16x8 a1 = *(const bf16x8*)(hp + ((kk + 1) << 5));
          acc = __builtin_amdgcn_mfma_f32_16x16x32_bf16(
              a0, *(const bf16x8*)(wb + ((((kk << 2) + kq) ^ rx) << 3)), acc, 0, 0, 0);
          acc2 = __builtin_amdgcn_mfma_f32_16x16x32_bf16(
              a1, *(const bf16x8*)(wb + (((((kk + 1) << 2) + kq) ^ rx) << 3)), acc2, 0, 0, 0);
        }
      }
      for (int r = 0; r < 4; ++r)
        glds[(w << 8) + (((kq << 2) + r) << 4) + r16] = acc[r] + acc2[r];
      __syncthreads();

      float xi = glds[(bidx << 4) + jl] + gi;
      float xf = glds[256 + (bidx << 4) + jl] + gf;
      float xg = glds[512 + (bidx << 4) + jl] + gg2;
      float xo = glds[768 + (bidx << 4) + jl] + go_;
      float ig = 1.f / (1.f + __expf(-xi));
      float fg = 1.f / (1.f + __expf(-xf));
      float eg = __expf(2.f * xg);
      float ggv = 1.f - 2.f / (eg + 1.f);
      float og = 1.f / (1.f + __expf(-xo));
      cst = fg * cst + ig * ggv;
      float ec = __expf(2.f * cst);
      float th = 1.f - 2.f / (ec + 1.f);
      bf16 hb = (bf16)(og * th);
      unsigned hu = (unsigned)__builtin_bit_cast(unsigned short, hb);
      unsigned other = (unsigned)__shfl_xor((int)hu, 1, 64);
      if (!(tid & 1)) {
        unsigned pair = (hu & 0xffffu) | (other << 16);
        bf16* sp = hs0 + ((((size_t)t << 4) + bidx) << 10) + j0 + jl;
        asm volatile("global_store_dword %0, %1, off sc1" ::"v"(sp), "v"(pair) : "memory");
      }
      asm volatile("s_waitcnt vmcnt(0)" ::: "memory");
      __syncthreads();  // all waves' write-through stores MALL-acked

      // fan-out signal: lane l -> consumer l's flag row (1 store/lane)
      const unsigned ep = (unsigned)(t + 1);
      if (w == 0)
        __hip_atomic_store(done0 + (l << 6) + bid, ep, __ATOMIC_RELAXED,
                           __HIP_MEMORY_SCOPE_AGENT);
      else if (w == 1)
        __hip_atomic_store(done01 + (l << 6) + bid, ep, __ATOMIC_RELAXED,
                           __HIP_MEMORY_SCOPE_AGENT);
      else if (w == 2)
        __hip_atomic_store(done01 + ((64 + l) << 6) + bid, ep, __ATOMIC_RELAXED,
                           __HIP_MEMORY_SCOPE_AGENT);
    }
  } else {
    const int q = bid - 64;  // 0..127
    const int j0 = q << 3;
    const int b1 = tid >> 3, j1 = tid & 7;
    float cst = 0.f;
    float bi_ = 0.f, bf_ = 0.f, bg_ = 0.f, bo_ = 0.f;
    if (tid < 128) {
      bi_ = bsum1[j0 + j1];
      bf_ = bsum1[1024 + j0 + j1];
      bg_ = bsum1[2048 + j0 + j1];
      bo_ = bsum1[3072 + j0 + j1];
    }

    for (int t1 = 0; t1 < T; ++t1) {
      // wait: h0[t1] ready (done01 row >= t1+1); h1[t1-1] ready (done1 row >= t1)
      if (w == 0) {
        const unsigned* fp = done01 + (q << 6) + l;
        while (__hip_atomic_load(fp, __ATOMIC_RELAXED, __HIP_MEMORY_SCOPE_AGENT) <
               (unsigned)(t1 + 1)) {
        }
      } else if (w == 1 && t1 > 0) {
        const unsigned* fp = done1 + (q << 7) + l;
        while (__hip_atomic_load(fp, __ATOMIC_RELAXED, __HIP_MEMORY_SCOPE_AGENT) <
               (unsigned)t1) {
        }
      } else if (w == 2 && t1 > 0) {
        const unsigned* fp = done1 + (q << 7) + 64 + l;
        while (__hip_atomic_load(fp, __ATOMIC_RELAXED, __HIP_MEMORY_SCOPE_AGENT) <
               (unsigned)t1) {
        }
      }
      __syncthreads();
      asm volatile("" ::: "memory");

      f32x4 acc0 = (f32x4){0.f, 0.f, 0.f, 0.f};
      f32x4 acc1 = (f32x4){0.f, 0.f, 0.f, 0.f};
      const bf16* hp0 = hs0 + ((size_t)t1 << 14) + (r16 << 10) + (kq << 3);
      const bf16* wb0 = wlds + (((w << 3) + rx) << 10);       // Wih1 rows
      const bf16* wb1 = wlds + ((32 + (w << 3) + rx) << 10);  // Whh1 rows
#pragma unroll 8
      for (int kk = 0; kk < 32; ++kk) {
        bf16x8 a0 = *(const bf16x8*)(hp0 + (kk << 5));
        acc0 = __builtin_amdgcn_mfma_f32_16x16x32_bf16(
            a0, *(const bf16x8*)(wb0 + ((((kk << 2) + kq) ^ rx) << 3)), acc0, 0, 0, 0);
      }
      if (t1 > 0) {
        const bf16* hp1 = hs1 + ((size_t)(t1 - 1) << 14) + (r16 << 10) + (kq << 3);
#pragma unroll 8
        for (int kk = 0; kk < 32; ++kk) {
          bf16x8 a1 = *(const bf16x8*)(hp1 + (kk << 5));
          acc1 = __builtin_amdgcn_mfma_f32_16x16x32_bf16(
              a1, *(const bf16x8*)(wb1 + ((((kk << 2) + kq) ^ rx) << 3)), acc1, 0, 0, 0);
        }
      }
      for (int r = 0; r < 4; ++r)
        glds[(w << 8) + (((kq << 2) + r) << 4) + r16] = acc0[r] + acc1[r];
      __syncthreads();

      if (tid < 128) {
        float xi = glds[(b1 << 4) + j1] + bi_;
        float xf = glds[256 + (b1 << 4) + j1] + bf_;
        float xg = glds[512 + (b1 << 4) + j1] + bg_;
        float xo = glds[768 + (b1 << 4) + j1] + bo_;
        float ig = 1.f / (1.f + __expf(-xi));
        float fg = 1.f / (1.f + __expf(-xf));
        float eg = __expf(2.f * xg);
        float ggv = 1.f - 2.f / (eg + 1.f);
        float og = 1.f / (1.f + __expf(-xo));
        cst = fg * cst + ig * ggv;
        float ec = __expf(2.f * cst);
        float th = 1.f - 2.f / (ec + 1.f);
        bf16 hb = (bf16)(og * th);
        unsigned hu = (unsigned)__builtin_bit_cast(unsigned short, hb);
        unsigned other = (unsigned)__shfl_xor((int)hu, 1, 64);
        if (!(tid & 1)) {
          unsigned pair = (hu & 0xffffu) | (other << 16);
          bf16* sp = hs1 + ((((size_t)t1 << 4) + b1) << 10) + j0 + j1;
          asm volatile("global_store_dword %0, %1, off sc1" ::"v"(sp), "v"(pair) : "memory");
        }
      }
      asm volatile("s_waitcnt vmcnt(0)" ::: "memory");
      __syncthreads();

      const unsigned ep = (unsigned)(t1 + 1);
      if (w == 0)
        __hip_atomic_store(done1 + (l << 7) + q, ep, __ATOMIC_RELAXED,
                           __HIP_MEMORY_SCOPE_AGENT);
      else if (w == 1)
        __hip_atomic_store(done1 + ((64 + l) << 7) + q, ep, __ATOMIC_RELAXED,
                           __HIP_MEMORY_SCOPE_AGENT);
    }
  }
}

extern "C" void kernel_launch(void* const* d_in, const int* in_sizes, int n_in,
                              void* d_out, int out_size, void* d_ws, size_t ws_size,
                              hipStream_t stream) {
  const int* x = (const int*)d_in[0];
  const float* emb = (const float*)d_in[1];
  const float* Wih0 = (const float*)d_in[2];
  const float* Whh0 = (const float*)d_in[3];
  const float* bih0 = (const float*)d_in[4];
  const float* bhh0 = (const float*)d_in[5];
  const float* Wih1 = (const float*)d_in[6];
  const float* Whh1 = (const float*)d_in[7];
  const float* bih1 = (const float*)d_in[8];
  const float* bhh1 = (const float*)d_in[9];
  const float* Wout = (const float*)d_in[10];
  const float* bout = (const float*)d_in[11];

  const int T = 512, H = 1024, V = 32000;
  const int M = T * 16;
  const size_t bfb = (size_t)M * H * 2;  // 16 MiB bf16 plane

  char* p = (char*)d_ws;
  bf16* hs1 = (bf16*)p;           p += bfb;  // must survive into projection -> ws
  float* bsum0 = (float*)p;       p += 4096 * 4;
  float* bsum1 = (float*)p;       p += 4096 * 4;
  unsigned* flags = (unsigned*)p; p += FLAG_WORDS * 4;
  size_t base_need = (size_t)(p - (char*)d_ws);
  bf16 *xe, *hs0;
  if (ws_size >= base_need + 2 * bfb) {
    xe = (bf16*)p;
    hs0 = (bf16*)(p + bfb);
  } else {  // d_out tail is dead until projection overwrites it
    char* tail = (char*)d_out + (size_t)out_size * 4 - 2 * bfb;
    xe = (bf16*)tail;
    hs0 = (bf16*)(tail + bfb);
  }
  float* gx = (float*)d_out;  // 134 MB scratch at head of d_out

  init_misc<<<64, 256, 0, stream>>>(bih0, bhh0, bih1, bhh1, bsum0, bsum1, flags);
  embed_gather<<<M, 256, 0, stream>>>(x, emb, xe, T);
  gemm_bf16<0><<<(M / 128) * (4096 / 128), 256, 0, stream>>>(xe, Wih0, bsum0, gx, M, 4096, H, 0);
  lstm_pipe<<<NBLK_W, 256, 0, stream>>>(gx, Whh0, Wih1, Whh1, bsum1, hs0, hs1, flags, T);
  gemm_bf16<1><<<(M / 128) * (V / 128), 256, 0, stream>>>(hs1, Wout, bout, (float*)d_out, M, V, H, T);
}